// Round 1
// baseline (1059.193 us; speedup 1.0000x reference)
//
#include <hip/hip_runtime.h>

#define DEV __device__ __forceinline__

constexpr int FDIM = 128;
constexpr float LRELU_S = 0.2f;

DEV float wsum64(float v){
#pragma unroll
  for (int off = 32; off > 0; off >>= 1) v += __shfl_xor(v, off, 64);
  return v;
}
DEV float wmax64(float v){
#pragma unroll
  for (int off = 32; off > 0; off >>= 1) v = fmaxf(v, __shfl_xor(v, off, 64));
  return v;
}
DEV float lrelu(float x){ return x >= 0.f ? x : LRELU_S * x; }

// ---------------- CSR build ----------------
__global__ void k_init_deg(int* __restrict__ deg, int n){
  int i = blockIdx.x * 256 + threadIdx.x;
  if (i < n) deg[i] = 1;  // self-loop
}
__global__ void k_deg(const int* __restrict__ dst, int* __restrict__ deg, int e){
  int i = blockIdx.x * 256 + threadIdx.x;
  if (i < e) atomicAdd(&deg[dst[i]], 1);
}
__global__ void k_scan1(const int* __restrict__ deg, int* __restrict__ rp,
                        int* __restrict__ csum, int n){
  __shared__ int sd[256];
  int t = threadIdx.x, b = blockIdx.x;
  int base = b * 1024 + t * 4;
  int v0 = (base     < n) ? deg[base]     : 0;
  int v1 = (base + 1 < n) ? deg[base + 1] : 0;
  int v2 = (base + 2 < n) ? deg[base + 2] : 0;
  int v3 = (base + 3 < n) ? deg[base + 3] : 0;
  int tot = v0 + v1 + v2 + v3;
  sd[t] = tot;
  __syncthreads();
  for (int off = 1; off < 256; off <<= 1){
    int o = (t >= off) ? sd[t - off] : 0;
    __syncthreads();
    sd[t] += o;
    __syncthreads();
  }
  int excl = sd[t] - tot;
  if (base     < n) rp[base]     = excl;
  if (base + 1 < n) rp[base + 1] = excl + v0;
  if (base + 2 < n) rp[base + 2] = excl + v0 + v1;
  if (base + 3 < n) rp[base + 3] = excl + v0 + v1 + v2;
  if (t == 255) csum[b] = sd[255];
}
__global__ void k_scan2(int* __restrict__ csum, int nch){
  __shared__ int sd[128];
  int t = threadIdx.x;
  int my = (t < nch) ? csum[t] : 0;
  sd[t] = my;
  __syncthreads();
  for (int off = 1; off < 128; off <<= 1){
    int o = (t >= off) ? sd[t - off] : 0;
    __syncthreads();
    sd[t] += o;
    __syncthreads();
  }
  if (t < nch) csum[t] = sd[t] - my;
}
__global__ void k_scan3(int* __restrict__ rp, const int* __restrict__ csum,
                        int n, int total){
  int i = blockIdx.x * 256 + threadIdx.x;
  if (i < n) rp[i] += csum[i >> 10];
  if (i == n) rp[n] = total;
}
__global__ void k_cursor(int* __restrict__ cur, const int* __restrict__ rp, int n){
  int i = blockIdx.x * 256 + threadIdx.x;
  if (i < n) cur[i] = rp[i];
}
__global__ void k_fill(const int* __restrict__ src, const int* __restrict__ dst,
                       int* __restrict__ cur, int* __restrict__ col, int e, int n){
  int i = blockIdx.x * 256 + threadIdx.x;
  if (i >= e + n) return;
  int s, d;
  if (i < e){ s = src[i]; d = dst[i]; } else { s = i - e; d = s; }
  int pos = atomicAdd(&cur[d], 1);
  col[pos] = s;
}

// ---------------- GEMM: out[M,128] = A[M,128] @ W[128,128] (fp32) ----------------
__global__ __launch_bounds__(256)
void gemm128(const float* __restrict__ A, const float* __restrict__ Wt,
             float* __restrict__ out, int M){
  __shared__ __align__(16) float Ws[32 * 128];   // 16 KB  [k][c], chunk of 32 k
  __shared__ __align__(16) float Xs[32 * 68];    // 8.7 KB [k][r], padded 64->68
  int tid = threadIdx.x;
  int row0 = blockIdx.x * 64;
  int tx = tid & 15, ty = tid >> 4;
  int r = tid >> 2, q = tid & 3;
  float acc[4][8];
#pragma unroll
  for (int i = 0; i < 4; ++i)
#pragma unroll
    for (int j = 0; j < 8; ++j) acc[i][j] = 0.f;

  for (int kk = 0; kk < 4; ++kk){
    // global loads (before barrier, overlap)
    float4 wv[4];
#pragma unroll
    for (int i2 = 0; i2 < 4; ++i2)
      wv[i2] = ((const float4*)Wt)[kk * 1024 + i2 * 256 + tid];
    int xrow = row0 + r;
    bool vr = xrow < M;
    float4 xv0 = make_float4(0.f, 0.f, 0.f, 0.f), xv1 = xv0;
    if (vr){
      const float* xp = A + (long long)xrow * FDIM + kk * 32 + q * 8;
      xv0 = *(const float4*)xp;
      xv1 = *(const float4*)(xp + 4);
    }
    __syncthreads();
#pragma unroll
    for (int i2 = 0; i2 < 4; ++i2) ((float4*)Ws)[i2 * 256 + tid] = wv[i2];
    {
      float t0[4] = {xv0.x, xv0.y, xv0.z, xv0.w};
      float t1[4] = {xv1.x, xv1.y, xv1.z, xv1.w};
#pragma unroll
      for (int u = 0; u < 4; ++u) Xs[(q * 8 + u) * 68 + r] = t0[u];
#pragma unroll
      for (int u = 0; u < 4; ++u) Xs[(q * 8 + 4 + u) * 68 + r] = t1[u];
    }
    __syncthreads();
#pragma unroll
    for (int k = 0; k < 32; ++k){
      const float4 av  = *(const float4*)&Xs[k * 68 + ty * 4];
      const float4 bv0 = *(const float4*)&Ws[k * 128 + tx * 8];
      const float4 bv1 = *(const float4*)&Ws[k * 128 + tx * 8 + 4];
      float as[4] = {av.x, av.y, av.z, av.w};
      float bs[8] = {bv0.x, bv0.y, bv0.z, bv0.w, bv1.x, bv1.y, bv1.z, bv1.w};
#pragma unroll
      for (int i = 0; i < 4; ++i)
#pragma unroll
        for (int j = 0; j < 8; ++j) acc[i][j] = fmaf(as[i], bs[j], acc[i][j]);
    }
  }
#pragma unroll
  for (int ii = 0; ii < 4; ++ii){
    int rr = row0 + ty * 4 + ii;
    if (rr < M){
      float4 o0 = make_float4(acc[ii][0], acc[ii][1], acc[ii][2], acc[ii][3]);
      float4 o1 = make_float4(acc[ii][4], acc[ii][5], acc[ii][6], acc[ii][7]);
      *(float4*)&out[(long long)rr * FDIM + tx * 8]     = o0;
      *(float4*)&out[(long long)rr * FDIM + tx * 8 + 4] = o1;
    }
  }
}

// ---------------- attention scores per node ----------------
template<int HEADS>
__global__ __launch_bounds__(256)
void k_attn(const float* __restrict__ feat, const float* __restrict__ att_s,
            const float* __restrict__ att_d, float* __restrict__ asb,
            float* __restrict__ adb, int n){
  int gw = (blockIdx.x * 256 + threadIdx.x) >> 6;
  if (gw >= n) return;
  int l = threadIdx.x & 63;
  int c0 = 2 * l;
  float2 f = *(const float2*)&feat[(long long)gw * FDIM + c0];
  if (HEADS == 4){
    int h = l >> 4, cc = c0 & 31;
    float sp = f.x * att_s[h * 32 + cc] + f.y * att_s[h * 32 + cc + 1];
    float dp = f.x * att_d[h * 32 + cc] + f.y * att_d[h * 32 + cc + 1];
#pragma unroll
    for (int off = 8; off >= 1; off >>= 1){
      sp += __shfl_xor(sp, off, 64);
      dp += __shfl_xor(dp, off, 64);
    }
    if ((l & 15) == 0){ asb[gw * 4 + h] = sp; adb[gw * 4 + h] = dp; }
  } else {
    float sp = f.x * att_s[c0] + f.y * att_s[c0 + 1];
    float dp = f.x * att_d[c0] + f.y * att_d[c0 + 1];
#pragma unroll
    for (int off = 32; off >= 1; off >>= 1){
      sp += __shfl_xor(sp, off, 64);
      dp += __shfl_xor(dp, off, 64);
    }
    if (l == 0){ asb[gw] = sp; adb[gw] = dp; }
  }
}

// ---------------- aggregation + epilogue (one wave per dst node) ----------------
// MODE 0: +bias, LayerNorm, PReLU, +residual   MODE 1: +bias, +residual
template<int HEADS, int MODE>
__global__ __launch_bounds__(256)
void k_agg(const float* __restrict__ feat, const float* __restrict__ asb,
           const float* __restrict__ adb, const int* __restrict__ rp,
           const int* __restrict__ col, const float* __restrict__ bias,
           const float* __restrict__ gamma, const float* __restrict__ beta,
           const float* __restrict__ prw, const float* __restrict__ resid,
           float* __restrict__ out, int n){
  int i = (blockIdx.x * 256 + threadIdx.x) >> 6;
  if (i >= n) return;
  int l = threadIdx.x & 63;
  int s = rp[i], epos = rp[i + 1];
  int h = (HEADS == 4) ? (l >> 4) : 0;
  int c0 = 2 * l;

  float ad0 = adb[i * HEADS];
  float ad1 = (HEADS == 4) ? adb[i * HEADS + 1] : 0.f;
  float ad2 = (HEADS == 4) ? adb[i * HEADS + 2] : 0.f;
  float ad3 = (HEADS == 4) ? adb[i * HEADS + 3] : 0.f;

  // pass 1: per-head max over neighbors
  float m0 = -1e30f, m1 = -1e30f, m2 = -1e30f, m3 = -1e30f;
  for (int base = s; base < epos; base += 64){
    int j = base + l;
    if (j < epos){
      int sj = col[j];
      if (HEADS == 4){
        float4 a4 = *(const float4*)&asb[sj * 4];
        m0 = fmaxf(m0, lrelu(a4.x + ad0));
        m1 = fmaxf(m1, lrelu(a4.y + ad1));
        m2 = fmaxf(m2, lrelu(a4.z + ad2));
        m3 = fmaxf(m3, lrelu(a4.w + ad3));
      } else {
        m0 = fmaxf(m0, lrelu(asb[sj] + ad0));
      }
    }
  }
  m0 = wmax64(m0);
  if (HEADS == 4){ m1 = wmax64(m1); m2 = wmax64(m2); m3 = wmax64(m3); }

  // pass 2: per-head sum of exp
  float d0 = 0.f, d1 = 0.f, d2 = 0.f, d3 = 0.f;
  for (int base = s; base < epos; base += 64){
    int j = base + l;
    if (j < epos){
      int sj = col[j];
      if (HEADS == 4){
        float4 a4 = *(const float4*)&asb[sj * 4];
        d0 += __expf(lrelu(a4.x + ad0) - m0);
        d1 += __expf(lrelu(a4.y + ad1) - m1);
        d2 += __expf(lrelu(a4.z + ad2) - m2);
        d3 += __expf(lrelu(a4.w + ad3) - m3);
      } else {
        d0 += __expf(lrelu(asb[sj] + ad0) - m0);
      }
    }
  }
  d0 = wsum64(d0);
  if (HEADS == 4){ d1 = wsum64(d1); d2 = wsum64(d2); d3 = wsum64(d3); }

  float mh  = (HEADS == 1) ? m0 : (h < 2 ? (h == 0 ? m0 : m1) : (h == 2 ? m2 : m3));
  float dh  = (HEADS == 1) ? d0 : (h < 2 ? (h == 0 ? d0 : d1) : (h == 2 ? d2 : d3));
  float adh = (HEADS == 1) ? ad0 : (h < 2 ? (h == 0 ? ad0 : ad1) : (h == 2 ? ad2 : ad3));

  // pass 3: weighted feature gather (2 channels per lane)
  float acc0 = 0.f, acc1 = 0.f;
  for (int base = s; base < epos; base += 64){
    int j = base + l;
    int myS = (j < epos) ? col[j] : 0;
    int cnt = epos - base; if (cnt > 64) cnt = 64;
#pragma unroll 4
    for (int t = 0; t < cnt; ++t){
      int sj = __shfl(myS, t, 64);
      float asv = asb[sj * HEADS + h];
      float w = __expf(lrelu(asv + adh) - mh);
      float2 f = *(const float2*)&feat[(long long)sj * FDIM + c0];
      acc0 = fmaf(w, f.x, acc0);
      acc1 = fmaf(w, f.y, acc1);
    }
  }
  float inv = 1.f / (dh + 1e-16f);
  float r0 = fmaf(acc0, inv, bias[c0]);
  float r1 = fmaf(acc1, inv, bias[c0 + 1]);
  float2 rs = *(const float2*)&resid[(long long)i * FDIM + c0];
  float2 o;
  if (MODE == 0){
    float mean = wsum64(r0 + r1) * (1.f / 128.f);
    float dd0 = r0 - mean, dd1 = r1 - mean;
    float var = wsum64(dd0 * dd0 + dd1 * dd1) * (1.f / 128.f);
    float rstd = rsqrtf(var + 1e-5f);
    float p = prw[0];
    float y0 = dd0 * rstd * gamma[c0]     + beta[c0];
    float y1 = dd1 * rstd * gamma[c0 + 1] + beta[c0 + 1];
    y0 = (y0 >= 0.f) ? y0 : p * y0;
    y1 = (y1 >= 0.f) ? y1 : p * y1;
    o.x = y0 + rs.x; o.y = y1 + rs.y;
  } else {
    o.x = r0 + rs.x; o.y = r1 + rs.y;
  }
  *(float2*)&out[(long long)i * FDIM + c0] = o;
}

// ---------------- launch ----------------
static inline int cdiv(int a, int b){ return (a + b - 1) / b; }

extern "C" void kernel_launch(void* const* d_in, const int* in_sizes, int n_in,
                              void* d_out, int out_size, void* d_ws, size_t ws_size,
                              hipStream_t stream){
  const float* x     = (const float*)d_in[0];
  const int*   eidx  = (const int*)d_in[1];
  const float* W0    = (const float*)d_in[2];
  const float* asr0  = (const float*)d_in[3];
  const float* adt0  = (const float*)d_in[4];
  const float* b0    = (const float*)d_in[5];
  const float* g0    = (const float*)d_in[6];
  const float* be0   = (const float*)d_in[7];
  const float* p0    = (const float*)d_in[8];
  const float* W1    = (const float*)d_in[9];
  const float* asr1  = (const float*)d_in[10];
  const float* adt1  = (const float*)d_in[11];
  const float* b1    = (const float*)d_in[12];
  const float* g1    = (const float*)d_in[13];
  const float* be1   = (const float*)d_in[14];
  const float* p1    = (const float*)d_in[15];
  const float* W2    = (const float*)d_in[16];
  const float* asr2  = (const float*)d_in[17];
  const float* adt2  = (const float*)d_in[18];
  const float* b2    = (const float*)d_in[19];

  const int N = in_sizes[0] / FDIM;     // 100000
  const int E = in_sizes[1] / 2;        // 1600000
  const int TOT = E + N;

  // workspace carve (256B aligned)
  char* p = (char*)d_ws;
  auto alloc = [&](size_t bytes) -> void* {
    void* r = (void*)p;
    p += (bytes + 255) & ~(size_t)255;
    return r;
  };
  int*   deg    = (int*)  alloc((size_t)N * 4);
  int*   rp     = (int*)  alloc((size_t)(N + 1) * 4);
  int*   cur    = (int*)  alloc((size_t)N * 4);
  int*   csum   = (int*)  alloc(128 * 4);
  int*   col    = (int*)  alloc((size_t)TOT * 4);
  float* feat   = (float*)alloc((size_t)N * FDIM * 4);
  float* asb    = (float*)alloc((size_t)N * 4 * 4);
  float* adb    = (float*)alloc((size_t)N * 4 * 4);
  float* hA     = (float*)alloc((size_t)N * FDIM * 4);
  float* hB     = (float*)alloc((size_t)N * FDIM * 4);
  (void)ws_size; (void)n_in; (void)out_size;

  const int nch = cdiv(N, 1024);

  // ---- CSR build (dst-sorted, shared by all 3 layers) ----
  k_init_deg<<<cdiv(N, 256), 256, 0, stream>>>(deg, N);
  k_deg<<<cdiv(E, 256), 256, 0, stream>>>(eidx + E, deg, E);
  k_scan1<<<nch, 256, 0, stream>>>(deg, rp, csum, N);
  k_scan2<<<1, 128, 0, stream>>>(csum, nch);
  k_scan3<<<cdiv(N + 1, 256), 256, 0, stream>>>(rp, csum, N, TOT);
  k_cursor<<<cdiv(N, 256), 256, 0, stream>>>(cur, rp, N);
  k_fill<<<cdiv(TOT, 256), 256, 0, stream>>>(eidx, eidx + E, cur, col, E, N);

  const int gB = cdiv(N, 64);   // gemm blocks
  const int nB = cdiv(N, 4);    // node-wave blocks (4 waves/block)

  // ---- block 0 ----
  gemm128<<<gB, 256, 0, stream>>>(x, W0, feat, N);
  k_attn<4><<<nB, 256, 0, stream>>>(feat, asr0, adt0, asb, adb, N);
  k_agg<4, 0><<<nB, 256, 0, stream>>>(feat, asb, adb, rp, col, b0, g0, be0, p0, x, hA, N);
  // ---- block 1 ----
  gemm128<<<gB, 256, 0, stream>>>(hA, W1, feat, N);
  k_attn<4><<<nB, 256, 0, stream>>>(feat, asr1, adt1, asb, adb, N);
  k_agg<4, 0><<<nB, 256, 0, stream>>>(feat, asb, adb, rp, col, b1, g1, be1, p1, hA, hB, N);
  // ---- block 2 ----
  gemm128<<<gB, 256, 0, stream>>>(hB, W2, feat, N);
  k_attn<1><<<nB, 256, 0, stream>>>(feat, asr2, adt2, asb, adb, N);
  k_agg<1, 1><<<nB, 256, 0, stream>>>(feat, asb, adb, rp, col, b2, nullptr, nullptr,
                                      nullptr, hB, (float*)d_out, N);
}

// Round 2
// 926.815 us; speedup vs baseline: 1.1428x; 1.1428x over previous
//
#include <hip/hip_runtime.h>

#define DEV __device__ __forceinline__

constexpr int FDIM = 128;
constexpr float LRELU_S = 0.2f;

DEV float wsum64(float v){
#pragma unroll
  for (int off = 32; off > 0; off >>= 1) v += __shfl_xor(v, off, 64);
  return v;
}
DEV float wmax64(float v){
#pragma unroll
  for (int off = 32; off > 0; off >>= 1) v = fmaxf(v, __shfl_xor(v, off, 64));
  return v;
}
DEV float lrelu(float x){ return x >= 0.f ? x : LRELU_S * x; }

// ---------------- CSR build ----------------
__global__ void k_init_deg(int* __restrict__ deg, int n){
  int i = blockIdx.x * 256 + threadIdx.x;
  if (i < n) deg[i] = 1;  // self-loop
}
__global__ void k_deg(const int* __restrict__ dst, int* __restrict__ deg, int e){
  int i = blockIdx.x * 256 + threadIdx.x;
  if (i < e) atomicAdd(&deg[dst[i]], 1);
}
__global__ void k_scan1(const int* __restrict__ deg, int* __restrict__ rp,
                        int* __restrict__ csum, int n){
  __shared__ int sd[256];
  int t = threadIdx.x, b = blockIdx.x;
  int base = b * 1024 + t * 4;
  int v0 = (base     < n) ? deg[base]     : 0;
  int v1 = (base + 1 < n) ? deg[base + 1] : 0;
  int v2 = (base + 2 < n) ? deg[base + 2] : 0;
  int v3 = (base + 3 < n) ? deg[base + 3] : 0;
  int tot = v0 + v1 + v2 + v3;
  sd[t] = tot;
  __syncthreads();
  for (int off = 1; off < 256; off <<= 1){
    int o = (t >= off) ? sd[t - off] : 0;
    __syncthreads();
    sd[t] += o;
    __syncthreads();
  }
  int excl = sd[t] - tot;
  if (base     < n) rp[base]     = excl;
  if (base + 1 < n) rp[base + 1] = excl + v0;
  if (base + 2 < n) rp[base + 2] = excl + v0 + v1;
  if (base + 3 < n) rp[base + 3] = excl + v0 + v1 + v2;
  if (t == 255) csum[b] = sd[255];
}
__global__ void k_scan2(int* __restrict__ csum, int nch){
  __shared__ int sd[128];
  int t = threadIdx.x;
  int my = (t < nch) ? csum[t] : 0;
  sd[t] = my;
  __syncthreads();
  for (int off = 1; off < 128; off <<= 1){
    int o = (t >= off) ? sd[t - off] : 0;
    __syncthreads();
    sd[t] += o;
    __syncthreads();
  }
  if (t < nch) csum[t] = sd[t] - my;
}
__global__ void k_scan3(int* __restrict__ rp, int* __restrict__ cur,
                        const int* __restrict__ csum, int n, int total){
  int i = blockIdx.x * 256 + threadIdx.x;
  if (i < n){ int v = rp[i] + csum[i >> 10]; rp[i] = v; cur[i] = v; }
  if (i == n) rp[n] = total;
}
__global__ void k_fill(const int* __restrict__ src, const int* __restrict__ dst,
                       int* __restrict__ cur, int* __restrict__ col, int e, int n){
  int i = blockIdx.x * 256 + threadIdx.x;
  if (i >= e + n) return;
  int s, d;
  if (i < e){ s = src[i]; d = dst[i]; } else { s = i - e; d = s; }
  int pos = atomicAdd(&cur[d], 1);
  col[pos] = s;
}

// -------- GEMM: out[M,128] = A[M,128] @ W[128,128] (fp32), fused attn scores --------
template<int HEADS>
__global__ __launch_bounds__(256)
void gemm128(const float* __restrict__ A, const float* __restrict__ Wt,
             const float* __restrict__ att_s, const float* __restrict__ att_d,
             float* __restrict__ out, float* __restrict__ asb,
             float* __restrict__ adb, int M){
  __shared__ __align__(16) float Ws[32 * 128];   // 16 KB  [k][c]
  __shared__ __align__(16) float Xs[32 * 68];    // 8.7 KB [k][r], padded
  int tid = threadIdx.x;
  int row0 = blockIdx.x * 64;
  int tx = tid & 15, ty = tid >> 4;
  int r = tid >> 2, q = tid & 3;
  float acc[4][8];
#pragma unroll
  for (int i = 0; i < 4; ++i)
#pragma unroll
    for (int j = 0; j < 8; ++j) acc[i][j] = 0.f;

  for (int kk = 0; kk < 4; ++kk){
    float4 wv[4];
#pragma unroll
    for (int i2 = 0; i2 < 4; ++i2)
      wv[i2] = ((const float4*)Wt)[kk * 1024 + i2 * 256 + tid];
    int xrow = row0 + r;
    bool vr = xrow < M;
    float4 xv0 = make_float4(0.f, 0.f, 0.f, 0.f), xv1 = xv0;
    if (vr){
      const float* xp = A + (long long)xrow * FDIM + kk * 32 + q * 8;
      xv0 = *(const float4*)xp;
      xv1 = *(const float4*)(xp + 4);
    }
    __syncthreads();
#pragma unroll
    for (int i2 = 0; i2 < 4; ++i2) ((float4*)Ws)[i2 * 256 + tid] = wv[i2];
    {
      float t0[4] = {xv0.x, xv0.y, xv0.z, xv0.w};
      float t1[4] = {xv1.x, xv1.y, xv1.z, xv1.w};
#pragma unroll
      for (int u = 0; u < 4; ++u) Xs[(q * 8 + u) * 68 + r] = t0[u];
#pragma unroll
      for (int u = 0; u < 4; ++u) Xs[(q * 8 + 4 + u) * 68 + r] = t1[u];
    }
    __syncthreads();
#pragma unroll
    for (int k = 0; k < 32; ++k){
      const float4 av  = *(const float4*)&Xs[k * 68 + ty * 4];
      const float4 bv0 = *(const float4*)&Ws[k * 128 + tx * 8];
      const float4 bv1 = *(const float4*)&Ws[k * 128 + tx * 8 + 4];
      float as[4] = {av.x, av.y, av.z, av.w};
      float bs[8] = {bv0.x, bv0.y, bv0.z, bv0.w, bv1.x, bv1.y, bv1.z, bv1.w};
#pragma unroll
      for (int i = 0; i < 4; ++i)
#pragma unroll
        for (int j = 0; j < 8; ++j) acc[i][j] = fmaf(as[i], bs[j], acc[i][j]);
    }
  }
  // attention coefficients for my 8 columns
  float as8[8], ad8[8];
  {
    float4 a0 = *(const float4*)&att_s[tx * 8];
    float4 a1 = *(const float4*)&att_s[tx * 8 + 4];
    float4 d0 = *(const float4*)&att_d[tx * 8];
    float4 d1 = *(const float4*)&att_d[tx * 8 + 4];
    as8[0]=a0.x; as8[1]=a0.y; as8[2]=a0.z; as8[3]=a0.w;
    as8[4]=a1.x; as8[5]=a1.y; as8[6]=a1.z; as8[7]=a1.w;
    ad8[0]=d0.x; ad8[1]=d0.y; ad8[2]=d0.z; ad8[3]=d0.w;
    ad8[4]=d1.x; ad8[5]=d1.y; ad8[6]=d1.z; ad8[7]=d1.w;
  }
#pragma unroll
  for (int ii = 0; ii < 4; ++ii){
    int rr = row0 + ty * 4 + ii;
    float ps = 0.f, pd = 0.f;
#pragma unroll
    for (int j = 0; j < 8; ++j){
      ps = fmaf(acc[ii][j], as8[j], ps);
      pd = fmaf(acc[ii][j], ad8[j], pd);
    }
    if (HEADS == 4){
      ps += __shfl_xor(ps, 1, 64); ps += __shfl_xor(ps, 2, 64);
      pd += __shfl_xor(pd, 1, 64); pd += __shfl_xor(pd, 2, 64);
      if ((tx & 3) == 0 && rr < M){
        asb[rr * 4 + (tx >> 2)] = ps;
        adb[rr * 4 + (tx >> 2)] = pd;
      }
    } else {
#pragma unroll
      for (int off = 8; off >= 1; off >>= 1){
        ps += __shfl_xor(ps, off, 64);
        pd += __shfl_xor(pd, off, 64);
      }
      if (tx == 0 && rr < M){ asb[rr] = ps; adb[rr] = pd; }
    }
    if (rr < M){
      float4 o0 = make_float4(acc[ii][0], acc[ii][1], acc[ii][2], acc[ii][3]);
      float4 o1 = make_float4(acc[ii][4], acc[ii][5], acc[ii][6], acc[ii][7]);
      *(float4*)&out[(long long)rr * FDIM + tx * 8]     = o0;
      *(float4*)&out[(long long)rr * FDIM + tx * 8 + 4] = o1;
    }
  }
}

// ---------------- aggregation + epilogue (one wave per dst node) ----------------
// MODE 0: +bias, LayerNorm, PReLU, +residual   MODE 1: +bias, +residual
template<int HEADS, int MODE>
__global__ __launch_bounds__(256)
void k_agg(const float* __restrict__ feat, const float* __restrict__ asb,
           const float* __restrict__ adb, const int* __restrict__ rp,
           const int* __restrict__ col, const float* __restrict__ bias,
           const float* __restrict__ gamma, const float* __restrict__ beta,
           const float* __restrict__ prw, const float* __restrict__ resid,
           float* __restrict__ out, int n){
  __shared__ float wbuf[4][64 * HEADS];
  __shared__ int   sbuf[4][64];
  int wid = threadIdx.x >> 6;
  int i = (blockIdx.x * 256 + threadIdx.x) >> 6;
  if (i >= n) return;
  int l = threadIdx.x & 63;
  int s = rp[i], epos = rp[i + 1];
  int h = (HEADS == 4) ? (l >> 4) : 0;
  int c0 = 2 * l;

  float ad0, ad1 = 0.f, ad2 = 0.f, ad3 = 0.f;
  if (HEADS == 4){
    float4 adv = *(const float4*)&adb[i * 4];
    ad0 = adv.x; ad1 = adv.y; ad2 = adv.z; ad3 = adv.w;
  } else {
    ad0 = adb[i];
  }

  // pass 1: per-head max over neighbors
  float m0 = -1e30f, m1 = -1e30f, m2 = -1e30f, m3 = -1e30f;
  for (int base = s; base < epos; base += 64){
    int j = base + l;
    if (j < epos){
      int sj = col[j];
      if (HEADS == 4){
        float4 a4 = *(const float4*)&asb[sj * 4];
        m0 = fmaxf(m0, lrelu(a4.x + ad0));
        m1 = fmaxf(m1, lrelu(a4.y + ad1));
        m2 = fmaxf(m2, lrelu(a4.z + ad2));
        m3 = fmaxf(m3, lrelu(a4.w + ad3));
      } else {
        m0 = fmaxf(m0, lrelu(asb[sj] + ad0));
      }
    }
  }
  m0 = wmax64(m0);
  if (HEADS == 4){ m1 = wmax64(m1); m2 = wmax64(m2); m3 = wmax64(m3); }

  // fused pass 2+3: per-lane weight computation (4 exps/edge), LDS park,
  // serial walk with broadcast reads; denominator accumulated in registers.
  float den0 = 0.f, den1 = 0.f, den2 = 0.f, den3 = 0.f;
  float acc0 = 0.f, acc1 = 0.f;
  for (int base = s; base < epos; base += 64){
    int j = base + l;
    int myS = 0;
    float w0 = 0.f, w1 = 0.f, w2 = 0.f, w3 = 0.f;
    if (j < epos){
      myS = col[j];
      if (HEADS == 4){
        float4 a4 = *(const float4*)&asb[myS * 4];
        w0 = __expf(lrelu(a4.x + ad0) - m0); den0 += w0;
        w1 = __expf(lrelu(a4.y + ad1) - m1); den1 += w1;
        w2 = __expf(lrelu(a4.z + ad2) - m2); den2 += w2;
        w3 = __expf(lrelu(a4.w + ad3) - m3); den3 += w3;
      } else {
        w0 = __expf(lrelu(asb[myS] + ad0) - m0); den0 += w0;
      }
    }
    sbuf[wid][l] = myS;
    if (HEADS == 4)
      *(float4*)&wbuf[wid][l * 4] = make_float4(w0, w1, w2, w3);
    else
      wbuf[wid][l] = w0;
    __builtin_amdgcn_wave_barrier();
    int cnt = epos - base; if (cnt > 64) cnt = 64;
#pragma unroll 4
    for (int t = 0; t < cnt; ++t){
      int sj = sbuf[wid][t];
      float w = (HEADS == 4) ? wbuf[wid][t * 4 + h] : wbuf[wid][t];
      float2 f = *(const float2*)&feat[(long long)sj * FDIM + c0];
      acc0 = fmaf(w, f.x, acc0);
      acc1 = fmaf(w, f.y, acc1);
    }
    __builtin_amdgcn_wave_barrier();
  }
  den0 = wsum64(den0);
  if (HEADS == 4){ den1 = wsum64(den1); den2 = wsum64(den2); den3 = wsum64(den3); }
  float dh = (HEADS == 1) ? den0
           : (h < 2 ? (h == 0 ? den0 : den1) : (h == 2 ? den2 : den3));

  float inv = 1.f / (dh + 1e-16f);
  float r0 = fmaf(acc0, inv, bias[c0]);
  float r1 = fmaf(acc1, inv, bias[c0 + 1]);
  float2 rs = *(const float2*)&resid[(long long)i * FDIM + c0];
  float2 o;
  if (MODE == 0){
    float mean = wsum64(r0 + r1) * (1.f / 128.f);
    float dd0 = r0 - mean, dd1 = r1 - mean;
    float var = wsum64(dd0 * dd0 + dd1 * dd1) * (1.f / 128.f);
    float rstd = rsqrtf(var + 1e-5f);
    float p = prw[0];
    float y0 = dd0 * rstd * gamma[c0]     + beta[c0];
    float y1 = dd1 * rstd * gamma[c0 + 1] + beta[c0 + 1];
    y0 = (y0 >= 0.f) ? y0 : p * y0;
    y1 = (y1 >= 0.f) ? y1 : p * y1;
    o.x = y0 + rs.x; o.y = y1 + rs.y;
  } else {
    o.x = r0 + rs.x; o.y = r1 + rs.y;
  }
  *(float2*)&out[(long long)i * FDIM + c0] = o;
}

// ---------------- launch ----------------
static inline int cdiv(int a, int b){ return (a + b - 1) / b; }

extern "C" void kernel_launch(void* const* d_in, const int* in_sizes, int n_in,
                              void* d_out, int out_size, void* d_ws, size_t ws_size,
                              hipStream_t stream){
  const float* x     = (const float*)d_in[0];
  const int*   eidx  = (const int*)d_in[1];
  const float* W0    = (const float*)d_in[2];
  const float* asr0  = (const float*)d_in[3];
  const float* adt0  = (const float*)d_in[4];
  const float* b0    = (const float*)d_in[5];
  const float* g0    = (const float*)d_in[6];
  const float* be0   = (const float*)d_in[7];
  const float* p0    = (const float*)d_in[8];
  const float* W1    = (const float*)d_in[9];
  const float* asr1  = (const float*)d_in[10];
  const float* adt1  = (const float*)d_in[11];
  const float* b1    = (const float*)d_in[12];
  const float* g1    = (const float*)d_in[13];
  const float* be1   = (const float*)d_in[14];
  const float* p1    = (const float*)d_in[15];
  const float* W2    = (const float*)d_in[16];
  const float* asr2  = (const float*)d_in[17];
  const float* adt2  = (const float*)d_in[18];
  const float* b2    = (const float*)d_in[19];

  const int N = in_sizes[0] / FDIM;     // 100000
  const int E = in_sizes[1] / 2;        // 1600000
  const int TOT = E + N;

  char* p = (char*)d_ws;
  auto alloc = [&](size_t bytes) -> void* {
    void* r = (void*)p;
    p += (bytes + 255) & ~(size_t)255;
    return r;
  };
  int*   deg    = (int*)  alloc((size_t)N * 4);
  int*   rp     = (int*)  alloc((size_t)(N + 1) * 4);
  int*   cur    = (int*)  alloc((size_t)N * 4);
  int*   csum   = (int*)  alloc(128 * 4);
  int*   col    = (int*)  alloc((size_t)TOT * 4);
  float* feat   = (float*)alloc((size_t)N * FDIM * 4);
  float* asb    = (float*)alloc((size_t)N * 4 * 4);
  float* adb    = (float*)alloc((size_t)N * 4 * 4);
  float* hA     = (float*)alloc((size_t)N * FDIM * 4);
  float* hB     = (float*)alloc((size_t)N * FDIM * 4);
  (void)ws_size; (void)n_in; (void)out_size;

  const int nch = cdiv(N, 1024);

  // ---- CSR build (dst-sorted, shared by all 3 layers) ----
  k_init_deg<<<cdiv(N, 256), 256, 0, stream>>>(deg, N);
  k_deg<<<cdiv(E, 256), 256, 0, stream>>>(eidx + E, deg, E);
  k_scan1<<<nch, 256, 0, stream>>>(deg, rp, csum, N);
  k_scan2<<<1, 128, 0, stream>>>(csum, nch);
  k_scan3<<<cdiv(N + 1, 256), 256, 0, stream>>>(rp, cur, csum, N, TOT);
  k_fill<<<cdiv(TOT, 256), 256, 0, stream>>>(eidx, eidx + E, cur, col, E, N);

  const int gB = cdiv(N, 64);   // gemm blocks
  const int nB = cdiv(N, 4);    // node-wave blocks (4 waves/block)

  // ---- block 0 ----
  gemm128<4><<<gB, 256, 0, stream>>>(x, W0, asr0, adt0, feat, asb, adb, N);
  k_agg<4, 0><<<nB, 256, 0, stream>>>(feat, asb, adb, rp, col, b0, g0, be0, p0, x, hA, N);
  // ---- block 1 ----
  gemm128<4><<<gB, 256, 0, stream>>>(hA, W1, asr1, adt1, feat, asb, adb, N);
  k_agg<4, 0><<<nB, 256, 0, stream>>>(feat, asb, adb, rp, col, b1, g1, be1, p1, hA, hB, N);
  // ---- block 2 ----
  gemm128<1><<<gB, 256, 0, stream>>>(hB, W2, asr2, adt2, feat, asb, adb, N);
  k_agg<1, 1><<<nB, 256, 0, stream>>>(feat, asb, adb, rp, col, b2, nullptr, nullptr,
                                      nullptr, hB, (float*)d_out, N);
}

// Round 3
// 705.781 us; speedup vs baseline: 1.5007x; 1.3132x over previous
//
#include <hip/hip_runtime.h>

#define DEV __device__ __forceinline__

constexpr int FDIM = 128;
constexpr float LRELU_S = 0.2f;

typedef _Float16 half_t;
typedef _Float16 f16x2 __attribute__((ext_vector_type(2)));
typedef _Float16 f16x4 __attribute__((ext_vector_type(4)));
typedef _Float16 f16x8 __attribute__((ext_vector_type(8)));
typedef float    f32x4 __attribute__((ext_vector_type(4)));

DEV float wsum64(float v){
#pragma unroll
  for (int off = 32; off > 0; off >>= 1) v += __shfl_xor(v, off, 64);
  return v;
}
DEV float lrelu(float x){ return x >= 0.f ? x : LRELU_S * x; }

// ---------------- CSR build ----------------
__global__ void k_init_deg(int* __restrict__ deg, int n){
  int i = blockIdx.x * 256 + threadIdx.x;
  if (i < n) deg[i] = 1;  // self-loop
}
__global__ void k_deg(const int* __restrict__ dst, int* __restrict__ deg, int e){
  int i = blockIdx.x * 256 + threadIdx.x;
  if (i < e) atomicAdd(&deg[dst[i]], 1);
}
__global__ void k_scan1(const int* __restrict__ deg, int* __restrict__ rp,
                        int* __restrict__ csum, int n){
  __shared__ int sd[256];
  int t = threadIdx.x, b = blockIdx.x;
  int base = b * 1024 + t * 4;
  int v0 = (base     < n) ? deg[base]     : 0;
  int v1 = (base + 1 < n) ? deg[base + 1] : 0;
  int v2 = (base + 2 < n) ? deg[base + 2] : 0;
  int v3 = (base + 3 < n) ? deg[base + 3] : 0;
  int tot = v0 + v1 + v2 + v3;
  sd[t] = tot;
  __syncthreads();
  for (int off = 1; off < 256; off <<= 1){
    int o = (t >= off) ? sd[t - off] : 0;
    __syncthreads();
    sd[t] += o;
    __syncthreads();
  }
  int excl = sd[t] - tot;
  if (base     < n) rp[base]     = excl;
  if (base + 1 < n) rp[base + 1] = excl + v0;
  if (base + 2 < n) rp[base + 2] = excl + v0 + v1;
  if (base + 3 < n) rp[base + 3] = excl + v0 + v1 + v2;
  if (t == 255) csum[b] = sd[255];
}
__global__ void k_scan2(int* __restrict__ csum, int nch){
  __shared__ int sd[128];
  int t = threadIdx.x;
  int my = (t < nch) ? csum[t] : 0;
  sd[t] = my;
  __syncthreads();
  for (int off = 1; off < 128; off <<= 1){
    int o = (t >= off) ? sd[t - off] : 0;
    __syncthreads();
    sd[t] += o;
    __syncthreads();
  }
  if (t < nch) csum[t] = sd[t] - my;
}
__global__ void k_scan3(int* __restrict__ rp, int* __restrict__ cur,
                        const int* __restrict__ csum, int n, int total){
  int i = blockIdx.x * 256 + threadIdx.x;
  if (i < n){ int v = rp[i] + csum[i >> 10]; rp[i] = v; cur[i] = v; }
  if (i == n) rp[n] = total;
}
__global__ void k_fill(const int* __restrict__ src, const int* __restrict__ dst,
                       int* __restrict__ cur, int* __restrict__ col, int e, int n){
  int i = blockIdx.x * 256 + threadIdx.x;
  if (i >= e + n) return;
  int s, d;
  if (i < e){ s = src[i]; d = dst[i]; } else { s = i - e; d = s; }
  int pos = atomicAdd(&cur[d], 1);
  col[pos] = s;
}

// ====== MFMA GEMM: feat[M,128](fp16) = A[M,128](fp32) @ W[128,128](fp32)
// ====== + fused attention scores asb/adb
// tile 128x128, 256 thr (4 waves 2x2), fp16 inputs, fp32 acc.
template<int HEADS>
__global__ __launch_bounds__(256)
void gemm_mfma(const float* __restrict__ A, const float* __restrict__ W,
               const float* __restrict__ att_s, const float* __restrict__ att_d,
               half_t* __restrict__ feat, float* __restrict__ asb,
               float* __restrict__ adb, int M){
  __shared__ __align__(16) unsigned char lds[53248];
  half_t* Ah = (half_t*)lds;              // [128][72] halfs, K-chunk of 64 (18432 B)
  half_t* Wt = (half_t*)(lds + 18432);    // [n=128][k=128] stride 136 (34816 B)
  float*  tr = (float*)lds;               // epilogue: [4][32][68] f32 (34816 B)

  int tid = threadIdx.x;
  int row0 = blockIdx.x * 128;
  int wid = tid >> 6, l = tid & 63;
  int wr = wid >> 1, wc = wid & 1;
  int lr = l & 15, lk = (l >> 4) * 8;

  // ---- stage W transposed: Wt[n][k] ----
  for (int rep = 0; rep < 16; ++rep){
    int e = rep * 1024 + tid * 4;
    int k = e >> 7, n0 = e & 127;
    float4 wv = *(const float4*)(W + e);
    half_t h4[4] = {(half_t)wv.x, (half_t)wv.y, (half_t)wv.z, (half_t)wv.w};
    int sw = tid & 3;
#pragma unroll
    for (int ii = 0; ii < 4; ++ii){
      int i = ii ^ sw;
      Wt[(n0 + i) * 136 + k] = h4[i];
    }
  }

  f32x4 acc[4][4];
#pragma unroll
  for (int mt = 0; mt < 4; ++mt)
#pragma unroll
    for (int nt = 0; nt < 4; ++nt)
      acc[mt][nt] = (f32x4){0.f, 0.f, 0.f, 0.f};

  for (int kc = 0; kc < 2; ++kc){
    __syncthreads();
    // stage A chunk [128 rows][64 k] -> fp16
    for (int rep = 0; rep < 8; ++rep){
      int e = rep * 1024 + tid * 4;
      int r = e >> 6, c = e & 63;
      int gr = row0 + r;
      float4 av = make_float4(0.f, 0.f, 0.f, 0.f);
      if (gr < M) av = *(const float4*)(A + (long long)gr * FDIM + kc * 64 + c);
      f16x4 h4 = {(half_t)av.x, (half_t)av.y, (half_t)av.z, (half_t)av.w};
      *(f16x4*)&Ah[r * 72 + c] = h4;
    }
    __syncthreads();
#pragma unroll
    for (int ksl = 0; ksl < 2; ++ksl){
      f16x8 af[4], bf[4];
      int klds = ksl * 32 + lk;
      int kw   = kc * 64 + ksl * 32 + lk;
#pragma unroll
      for (int mt = 0; mt < 4; ++mt)
        af[mt] = *(const f16x8*)&Ah[(wr * 64 + mt * 16 + lr) * 72 + klds];
#pragma unroll
      for (int nt = 0; nt < 4; ++nt)
        bf[nt] = *(const f16x8*)&Wt[(wc * 64 + nt * 16 + lr) * 136 + kw];
#pragma unroll
      for (int mt = 0; mt < 4; ++mt)
#pragma unroll
        for (int nt = 0; nt < 4; ++nt)
          acc[mt][nt] = __builtin_amdgcn_mfma_f32_16x16x32_f16(af[mt], bf[nt],
                                                               acc[mt][nt], 0, 0, 0);
    }
  }

  // ---- epilogue: transpose via LDS (2 passes), fp16 feat + attention scores ----
  const int q  = tid & 3;     // column quarter (32 cols) == head when HEADS==4
  const int ri = tid >> 2;    // 0..63 row slot within pass
  for (int p = 0; p < 2; ++p){
    __syncthreads();
#pragma unroll
    for (int mtl = 0; mtl < 2; ++mtl){
      int mt = p * 2 + mtl;
#pragma unroll
      for (int j = 0; j < 4; ++j){
        int rowl = mtl * 16 + (l >> 4) * 4 + j;   // 0..31
        float* dstp = tr + (wid * 32 + rowl) * 68 + lr;
#pragma unroll
        for (int nt = 0; nt < 4; ++nt)
          dstp[nt * 16] = acc[mt][nt][j];
      }
    }
    __syncthreads();
    // readback: row index ri -> block row
    int br = (ri >> 5) * 64 + p * 32 + (ri & 31);
    int gr = row0 + br;
    const float* srcp = tr + (((ri >> 5) * 2 + (q >> 1)) * 32 + (ri & 31)) * 68
                          + (q & 1) * 32;
    float vals[32];
#pragma unroll
    for (int u = 0; u < 8; ++u){
      float4 v = *(const float4*)&srcp[u * 4];
      vals[u*4+0] = v.x; vals[u*4+1] = v.y; vals[u*4+2] = v.z; vals[u*4+3] = v.w;
    }
    float sc_s = 0.f, sc_d = 0.f;
#pragma unroll
    for (int cc = 0; cc < 32; ++cc){
      sc_s = fmaf(vals[cc], att_s[q * 32 + cc], sc_s);
      sc_d = fmaf(vals[cc], att_d[q * 32 + cc], sc_d);
    }
    if (HEADS == 4){
      if (gr < M){ asb[gr * 4 + q] = sc_s; adb[gr * 4 + q] = sc_d; }
    } else {
      sc_s += __shfl_xor(sc_s, 1, 64); sc_s += __shfl_xor(sc_s, 2, 64);
      sc_d += __shfl_xor(sc_d, 1, 64); sc_d += __shfl_xor(sc_d, 2, 64);
      if (q == 0 && gr < M){ asb[gr] = sc_s; adb[gr] = sc_d; }
    }
    if (gr < M){
#pragma unroll
      for (int u = 0; u < 4; ++u){
        f16x8 h8 = {(half_t)vals[u*8+0], (half_t)vals[u*8+1], (half_t)vals[u*8+2],
                    (half_t)vals[u*8+3], (half_t)vals[u*8+4], (half_t)vals[u*8+5],
                    (half_t)vals[u*8+6], (half_t)vals[u*8+7]};
        *(f16x8*)&feat[(long long)gr * FDIM + q * 32 + u * 8] = h8;
      }
    }
  }
}

// ---------------- aggregation + epilogue (one wave per dst node) ----------------
// single scan: per-lane weights (no max subtraction - scores bounded), LDS park,
// broadcast walk gathering fp16 feat. MODE 0: LN+PReLU+resid  MODE 1: +resid
template<int HEADS, int MODE>
__global__ __launch_bounds__(256)
void k_agg(const half_t* __restrict__ feat, const float* __restrict__ asb,
           const float* __restrict__ adb, const int* __restrict__ rp,
           const int* __restrict__ col, const float* __restrict__ bias,
           const float* __restrict__ gamma, const float* __restrict__ beta,
           const float* __restrict__ prw, const float* __restrict__ resid,
           float* __restrict__ out, int n){
  __shared__ float wbuf[4][64 * HEADS];
  __shared__ int   sbuf[4][64];
  int wid = threadIdx.x >> 6;
  int i = (blockIdx.x * 256 + threadIdx.x) >> 6;
  if (i >= n) return;
  int l = threadIdx.x & 63;
  int s = rp[i], epos = rp[i + 1];
  int h = (HEADS == 4) ? (l >> 4) : 0;
  int c0 = 2 * l;

  float ad0, ad1 = 0.f, ad2 = 0.f, ad3 = 0.f;
  if (HEADS == 4){
    float4 adv = *(const float4*)&adb[i * 4];
    ad0 = adv.x; ad1 = adv.y; ad2 = adv.z; ad3 = adv.w;
  } else {
    ad0 = adb[i];
  }

  float den0 = 0.f, den1 = 0.f, den2 = 0.f, den3 = 0.f;
  float acc0 = 0.f, acc1 = 0.f;
  for (int base = s; base < epos; base += 64){
    int j = base + l;
    int myS = 0;
    float w0 = 0.f, w1 = 0.f, w2 = 0.f, w3 = 0.f;
    if (j < epos){
      myS = col[j];
      if (HEADS == 4){
        float4 a4 = *(const float4*)&asb[myS * 4];
        w0 = __expf(lrelu(a4.x + ad0)); den0 += w0;
        w1 = __expf(lrelu(a4.y + ad1)); den1 += w1;
        w2 = __expf(lrelu(a4.z + ad2)); den2 += w2;
        w3 = __expf(lrelu(a4.w + ad3)); den3 += w3;
      } else {
        w0 = __expf(lrelu(asb[myS] + ad0)); den0 += w0;
      }
    }
    sbuf[wid][l] = myS;
    if (HEADS == 4)
      *(float4*)&wbuf[wid][l * 4] = make_float4(w0, w1, w2, w3);
    else
      wbuf[wid][l] = w0;
    __builtin_amdgcn_wave_barrier();
    int cnt = epos - base; if (cnt > 64) cnt = 64;
#pragma unroll 8
    for (int t = 0; t < cnt; ++t){
      int sj = sbuf[wid][t];
      float w = (HEADS == 4) ? wbuf[wid][t * 4 + h] : wbuf[wid][t];
      f16x2 f = *(const f16x2*)&feat[(long long)sj * FDIM + c0];
      acc0 = fmaf(w, (float)f[0], acc0);
      acc1 = fmaf(w, (float)f[1], acc1);
    }
    __builtin_amdgcn_wave_barrier();
  }
  den0 = wsum64(den0);
  if (HEADS == 4){ den1 = wsum64(den1); den2 = wsum64(den2); den3 = wsum64(den3); }
  float dh = (HEADS == 1) ? den0
           : (h < 2 ? (h == 0 ? den0 : den1) : (h == 2 ? den2 : den3));

  float inv = 1.f / (dh + 1e-16f);
  float r0 = fmaf(acc0, inv, bias[c0]);
  float r1 = fmaf(acc1, inv, bias[c0 + 1]);
  float2 rs = *(const float2*)&resid[(long long)i * FDIM + c0];
  float2 o;
  if (MODE == 0){
    float mean = wsum64(r0 + r1) * (1.f / 128.f);
    float dd0 = r0 - mean, dd1 = r1 - mean;
    float var = wsum64(dd0 * dd0 + dd1 * dd1) * (1.f / 128.f);
    float rstd = rsqrtf(var + 1e-5f);
    float p = prw[0];
    float y0 = dd0 * rstd * gamma[c0]     + beta[c0];
    float y1 = dd1 * rstd * gamma[c0 + 1] + beta[c0 + 1];
    y0 = (y0 >= 0.f) ? y0 : p * y0;
    y1 = (y1 >= 0.f) ? y1 : p * y1;
    o.x = y0 + rs.x; o.y = y1 + rs.y;
  } else {
    o.x = r0 + rs.x; o.y = r1 + rs.y;
  }
  *(float2*)&out[(long long)i * FDIM + c0] = o;
}

// ---------------- launch ----------------
static inline int cdiv(int a, int b){ return (a + b - 1) / b; }

extern "C" void kernel_launch(void* const* d_in, const int* in_sizes, int n_in,
                              void* d_out, int out_size, void* d_ws, size_t ws_size,
                              hipStream_t stream){
  const float* x     = (const float*)d_in[0];
  const int*   eidx  = (const int*)d_in[1];
  const float* W0    = (const float*)d_in[2];
  const float* asr0  = (const float*)d_in[3];
  const float* adt0  = (const float*)d_in[4];
  const float* b0    = (const float*)d_in[5];
  const float* g0    = (const float*)d_in[6];
  const float* be0   = (const float*)d_in[7];
  const float* p0    = (const float*)d_in[8];
  const float* W1    = (const float*)d_in[9];
  const float* asr1  = (const float*)d_in[10];
  const float* adt1  = (const float*)d_in[11];
  const float* b1    = (const float*)d_in[12];
  const float* g1    = (const float*)d_in[13];
  const float* be1   = (const float*)d_in[14];
  const float* p1    = (const float*)d_in[15];
  const float* W2    = (const float*)d_in[16];
  const float* asr2  = (const float*)d_in[17];
  const float* adt2  = (const float*)d_in[18];
  const float* b2    = (const float*)d_in[19];

  const int N = in_sizes[0] / FDIM;     // 100000
  const int E = in_sizes[1] / 2;        // 1600000
  const int TOT = E + N;

  char* p = (char*)d_ws;
  auto alloc = [&](size_t bytes) -> void* {
    void* r = (void*)p;
    p += (bytes + 255) & ~(size_t)255;
    return r;
  };
  int*    deg  = (int*)   alloc((size_t)N * 4);
  int*    rp   = (int*)   alloc((size_t)(N + 1) * 4);
  int*    cur  = (int*)   alloc((size_t)N * 4);
  int*    csum = (int*)   alloc(128 * 4);
  int*    col  = (int*)   alloc((size_t)TOT * 4);
  half_t* feat = (half_t*)alloc((size_t)N * FDIM * 2);
  float*  asb  = (float*) alloc((size_t)N * 4 * 4);
  float*  adb  = (float*) alloc((size_t)N * 4 * 4);
  float*  hA   = (float*) alloc((size_t)N * FDIM * 4);
  float*  hB   = (float*) alloc((size_t)N * FDIM * 4);
  (void)ws_size; (void)n_in; (void)out_size;

  const int nch = cdiv(N, 1024);

  // ---- CSR build (dst-sorted, shared by all 3 layers) ----
  k_init_deg<<<cdiv(N, 256), 256, 0, stream>>>(deg, N);
  k_deg<<<cdiv(E, 256), 256, 0, stream>>>(eidx + E, deg, E);
  k_scan1<<<nch, 256, 0, stream>>>(deg, rp, csum, N);
  k_scan2<<<1, 128, 0, stream>>>(csum, nch);
  k_scan3<<<cdiv(N + 1, 256), 256, 0, stream>>>(rp, cur, csum, N, TOT);
  k_fill<<<cdiv(TOT, 256), 256, 0, stream>>>(eidx, eidx + E, cur, col, E, N);

  const int gB = cdiv(N, 128);  // mfma gemm blocks
  const int nB = cdiv(N, 4);    // node-wave blocks (4 waves/block)

  // ---- block 0 ----
  gemm_mfma<4><<<gB, 256, 0, stream>>>(x, W0, asr0, adt0, feat, asb, adb, N);
  k_agg<4, 0><<<nB, 256, 0, stream>>>(feat, asb, adb, rp, col, b0, g0, be0, p0, x, hA, N);
  // ---- block 1 ----
  gemm_mfma<4><<<gB, 256, 0, stream>>>(hA, W1, asr1, adt1, feat, asb, adb, N);
  k_agg<4, 0><<<nB, 256, 0, stream>>>(feat, asb, adb, rp, col, b1, g1, be1, p1, hA, hB, N);
  // ---- block 2 ----
  gemm_mfma<1><<<gB, 256, 0, stream>>>(hB, W2, asr2, adt2, feat, asb, adb, N);
  k_agg<1, 1><<<nB, 256, 0, stream>>>(feat, asb, adb, rp, col, b2, nullptr, nullptr,
                                      nullptr, hB, (float*)d_out, N);
}

// Round 4
// 586.350 us; speedup vs baseline: 1.8064x; 1.2037x over previous
//
#include <hip/hip_runtime.h>

#define DEV __device__ __forceinline__

constexpr int FDIM = 128;
constexpr float LRELU_S = 0.2f;

typedef _Float16 half_t;
typedef _Float16 f16x2 __attribute__((ext_vector_type(2)));
typedef _Float16 f16x4 __attribute__((ext_vector_type(4)));
typedef _Float16 f16x8 __attribute__((ext_vector_type(8)));
typedef float    f32x4 __attribute__((ext_vector_type(4)));

DEV float wsum64(float v){
#pragma unroll
  for (int off = 32; off > 0; off >>= 1) v += __shfl_xor(v, off, 64);
  return v;
}
DEV float lrelu(float x){ return x >= 0.f ? x : LRELU_S * x; }

// ================= CSR build: LDS-bucketed counting sort =================
// bucket = dst >> 7  (128 nodes/bucket), NB <= 1024 buckets.

__global__ void k_bzero(int* __restrict__ bcnt, int nb){
  int i = blockIdx.x * 256 + threadIdx.x;
  if (i < nb) bcnt[i] = 0;
}

__global__ __launch_bounds__(256)
void k_bp1(const int* __restrict__ dst, int* __restrict__ bcnt, int e, int chunk){
  __shared__ int hist[1024];
  int t = threadIdx.x;
  int lo = blockIdx.x * chunk, hi = min(e, lo + chunk);
  for (int i = t; i < 1024; i += 256) hist[i] = 0;
  __syncthreads();
  for (int j = lo + t; j < hi; j += 256) atomicAdd(&hist[dst[j] >> 7], 1);
  __syncthreads();
  for (int i = t; i < 1024; i += 256){
    int c = hist[i];
    if (c) atomicAdd(&bcnt[i], c);
  }
}

// single-block exclusive scan over nb (<=1024) bucket counts
__global__ __launch_bounds__(256)
void k_bscan(const int* __restrict__ bcnt, int* __restrict__ boff,
             int* __restrict__ bcur, int nb, int e){
  __shared__ int sd[256];
  int t = threadIdx.x;
  int i0 = t * 4;
  int v[4]; int tot = 0;
#pragma unroll
  for (int j = 0; j < 4; ++j){
    v[j] = (i0 + j < nb) ? bcnt[i0 + j] : 0;
    tot += v[j];
  }
  sd[t] = tot;
  __syncthreads();
  for (int off = 1; off < 256; off <<= 1){
    int o = (t >= off) ? sd[t - off] : 0;
    __syncthreads();
    sd[t] += o;
    __syncthreads();
  }
  int run = sd[t] - tot;
#pragma unroll
  for (int j = 0; j < 4; ++j){
    if (i0 + j < nb){ boff[i0 + j] = run; bcur[i0 + j] = run; }
    run += v[j];
  }
  if (t == 0) boff[nb] = e;
}

__global__ __launch_bounds__(256)
void k_bp2(const int* __restrict__ src, const int* __restrict__ dst,
           int* __restrict__ bcur, int2* __restrict__ ebuf, int e, int chunk){
  __shared__ int hist[1024];
  __shared__ int base[1024];
  int t = threadIdx.x;
  int lo = blockIdx.x * chunk, hi = min(e, lo + chunk);
  for (int i = t; i < 1024; i += 256) hist[i] = 0;
  __syncthreads();
  for (int j = lo + t; j < hi; j += 256) atomicAdd(&hist[dst[j] >> 7], 1);
  __syncthreads();
  for (int i = t; i < 1024; i += 256){
    int c = hist[i];
    base[i] = c ? atomicAdd(&bcur[i], c) : 0;
    hist[i] = 0;
  }
  __syncthreads();
  for (int j = lo + t; j < hi; j += 256){
    int d = dst[j];
    int b = d >> 7;
    int r = atomicAdd(&hist[b], 1);
    ebuf[base[b] + r] = make_int2(src[j], d);
  }
}

__global__ __launch_bounds__(256)
void k_bdeg(const int2* __restrict__ ebuf, const int* __restrict__ boff,
            int* __restrict__ deg, int n){
  __shared__ int cnt[128];
  int b = blockIdx.x, t = threadIdx.x;
  if (t < 128) cnt[t] = 1;   // self-loop
  __syncthreads();
  int lo = boff[b], hi = boff[b + 1];
  for (int j = lo + t; j < hi; j += 256) atomicAdd(&cnt[ebuf[j].y & 127], 1);
  __syncthreads();
  int node = b * 128 + t;
  if (t < 128 && node < n) deg[node] = cnt[t];
}

__global__ void k_scan1(const int* __restrict__ deg, int* __restrict__ rp,
                        int* __restrict__ csum, int n){
  __shared__ int sd[256];
  int t = threadIdx.x, b = blockIdx.x;
  int base = b * 1024 + t * 4;
  int v0 = (base     < n) ? deg[base]     : 0;
  int v1 = (base + 1 < n) ? deg[base + 1] : 0;
  int v2 = (base + 2 < n) ? deg[base + 2] : 0;
  int v3 = (base + 3 < n) ? deg[base + 3] : 0;
  int tot = v0 + v1 + v2 + v3;
  sd[t] = tot;
  __syncthreads();
  for (int off = 1; off < 256; off <<= 1){
    int o = (t >= off) ? sd[t - off] : 0;
    __syncthreads();
    sd[t] += o;
    __syncthreads();
  }
  int excl = sd[t] - tot;
  if (base     < n) rp[base]     = excl;
  if (base + 1 < n) rp[base + 1] = excl + v0;
  if (base + 2 < n) rp[base + 2] = excl + v0 + v1;
  if (base + 3 < n) rp[base + 3] = excl + v0 + v1 + v2;
  if (t == 255) csum[b] = sd[255];
}
__global__ void k_scan2(int* __restrict__ csum, int nch){
  __shared__ int sd[128];
  int t = threadIdx.x;
  int my = (t < nch) ? csum[t] : 0;
  sd[t] = my;
  __syncthreads();
  for (int off = 1; off < 128; off <<= 1){
    int o = (t >= off) ? sd[t - off] : 0;
    __syncthreads();
    sd[t] += o;
    __syncthreads();
  }
  if (t < nch) csum[t] = sd[t] - my;
}
__global__ void k_scan3(int* __restrict__ rp, const int* __restrict__ csum,
                        int n, int total){
  int i = blockIdx.x * 256 + threadIdx.x;
  if (i < n) rp[i] += csum[i >> 10];
  if (i == n) rp[n] = total;
}

__global__ __launch_bounds__(256)
void k_bfill(const int2* __restrict__ ebuf, const int* __restrict__ boff,
             const int* __restrict__ rp, int* __restrict__ col, int n){
  __shared__ int cur2[128];
  int b = blockIdx.x, t = threadIdx.x;
  int node = b * 128 + t;
  if (t < 128 && node < n){
    int r0 = rp[node];
    col[r0] = node;          // self-loop first
    cur2[t] = r0 + 1;
  }
  __syncthreads();
  int lo = boff[b], hi = boff[b + 1];
  for (int j = lo + t; j < hi; j += 256){
    int2 ed = ebuf[j];
    int pos = atomicAdd(&cur2[ed.y & 127], 1);
    col[pos] = ed.x;
  }
}

// ====== MFMA GEMM: feat[M,128](fp16) = A[M,128](fp32) @ W[128,128](fp32)
// ====== + fused attention scores asb/adb
template<int HEADS>
__global__ __launch_bounds__(256)
void gemm_mfma(const float* __restrict__ A, const float* __restrict__ W,
               const float* __restrict__ att_s, const float* __restrict__ att_d,
               half_t* __restrict__ feat, float* __restrict__ asb,
               float* __restrict__ adb, int M){
  __shared__ __align__(16) unsigned char lds[53248];
  half_t* Ah = (half_t*)lds;              // [128][72] halfs, K-chunk of 64
  half_t* Wt = (half_t*)(lds + 18432);    // [n=128][k=128] stride 136
  float*  tr = (float*)lds;               // epilogue: [4][32][68] f32

  int tid = threadIdx.x;
  int row0 = blockIdx.x * 128;
  int wid = tid >> 6, l = tid & 63;
  int wr = wid >> 1, wc = wid & 1;
  int lr = l & 15, lk = (l >> 4) * 8;

  for (int rep = 0; rep < 16; ++rep){
    int e = rep * 1024 + tid * 4;
    int k = e >> 7, n0 = e & 127;
    float4 wv = *(const float4*)(W + e);
    half_t h4[4] = {(half_t)wv.x, (half_t)wv.y, (half_t)wv.z, (half_t)wv.w};
    int sw = tid & 3;
#pragma unroll
    for (int ii = 0; ii < 4; ++ii){
      int i = ii ^ sw;
      Wt[(n0 + i) * 136 + k] = h4[i];
    }
  }

  f32x4 acc[4][4];
#pragma unroll
  for (int mt = 0; mt < 4; ++mt)
#pragma unroll
    for (int nt = 0; nt < 4; ++nt)
      acc[mt][nt] = (f32x4){0.f, 0.f, 0.f, 0.f};

  for (int kc = 0; kc < 2; ++kc){
    __syncthreads();
    for (int rep = 0; rep < 8; ++rep){
      int e = rep * 1024 + tid * 4;
      int r = e >> 6, c = e & 63;
      int gr = row0 + r;
      float4 av = make_float4(0.f, 0.f, 0.f, 0.f);
      if (gr < M) av = *(const float4*)(A + (long long)gr * FDIM + kc * 64 + c);
      f16x4 h4 = {(half_t)av.x, (half_t)av.y, (half_t)av.z, (half_t)av.w};
      *(f16x4*)&Ah[r * 72 + c] = h4;
    }
    __syncthreads();
#pragma unroll
    for (int ksl = 0; ksl < 2; ++ksl){
      f16x8 af[4], bf[4];
      int klds = ksl * 32 + lk;
      int kw   = kc * 64 + ksl * 32 + lk;
#pragma unroll
      for (int mt = 0; mt < 4; ++mt)
        af[mt] = *(const f16x8*)&Ah[(wr * 64 + mt * 16 + lr) * 72 + klds];
#pragma unroll
      for (int nt = 0; nt < 4; ++nt)
        bf[nt] = *(const f16x8*)&Wt[(wc * 64 + nt * 16 + lr) * 136 + kw];
#pragma unroll
      for (int mt = 0; mt < 4; ++mt)
#pragma unroll
        for (int nt = 0; nt < 4; ++nt)
          acc[mt][nt] = __builtin_amdgcn_mfma_f32_16x16x32_f16(af[mt], bf[nt],
                                                               acc[mt][nt], 0, 0, 0);
    }
  }

  const int q  = tid & 3;
  const int ri = tid >> 2;
  for (int p = 0; p < 2; ++p){
    __syncthreads();
#pragma unroll
    for (int mtl = 0; mtl < 2; ++mtl){
      int mt = p * 2 + mtl;
#pragma unroll
      for (int j = 0; j < 4; ++j){
        int rowl = mtl * 16 + (l >> 4) * 4 + j;
        float* dstp = tr + (wid * 32 + rowl) * 68 + lr;
#pragma unroll
        for (int nt = 0; nt < 4; ++nt)
          dstp[nt * 16] = acc[mt][nt][j];
      }
    }
    __syncthreads();
    int br = (ri >> 5) * 64 + p * 32 + (ri & 31);
    int gr = row0 + br;
    const float* srcp = tr + (((ri >> 5) * 2 + (q >> 1)) * 32 + (ri & 31)) * 68
                          + (q & 1) * 32;
    float vals[32];
#pragma unroll
    for (int u = 0; u < 8; ++u){
      float4 v = *(const float4*)&srcp[u * 4];
      vals[u*4+0] = v.x; vals[u*4+1] = v.y; vals[u*4+2] = v.z; vals[u*4+3] = v.w;
    }
    float sc_s = 0.f, sc_d = 0.f;
#pragma unroll
    for (int cc = 0; cc < 32; ++cc){
      sc_s = fmaf(vals[cc], att_s[q * 32 + cc], sc_s);
      sc_d = fmaf(vals[cc], att_d[q * 32 + cc], sc_d);
    }
    if (HEADS == 4){
      if (gr < M){ asb[gr * 4 + q] = sc_s; adb[gr * 4 + q] = sc_d; }
    } else {
      sc_s += __shfl_xor(sc_s, 1, 64); sc_s += __shfl_xor(sc_s, 2, 64);
      sc_d += __shfl_xor(sc_d, 1, 64); sc_d += __shfl_xor(sc_d, 2, 64);
      if (q == 0 && gr < M){ asb[gr] = sc_s; adb[gr] = sc_d; }
    }
    if (gr < M){
#pragma unroll
      for (int u = 0; u < 4; ++u){
        f16x8 h8 = {(half_t)vals[u*8+0], (half_t)vals[u*8+1], (half_t)vals[u*8+2],
                    (half_t)vals[u*8+3], (half_t)vals[u*8+4], (half_t)vals[u*8+5],
                    (half_t)vals[u*8+6], (half_t)vals[u*8+7]};
        *(f16x8*)&feat[(long long)gr * FDIM + q * 32 + u * 8] = h8;
      }
    }
  }
}

// ---------------- aggregation + epilogue (one wave per dst node) ----------------
template<int HEADS, int MODE>
__global__ __launch_bounds__(256)
void k_agg(const half_t* __restrict__ feat, const float* __restrict__ asb,
           const float* __restrict__ adb, const int* __restrict__ rp,
           const int* __restrict__ col, const float* __restrict__ bias,
           const float* __restrict__ gamma, const float* __restrict__ beta,
           const float* __restrict__ prw, const float* __restrict__ resid,
           float* __restrict__ out, int n){
  __shared__ float wbuf[4][64 * HEADS];
  __shared__ int   sbuf[4][64];
  int wid = threadIdx.x >> 6;
  int i = (blockIdx.x * 256 + threadIdx.x) >> 6;
  if (i >= n) return;
  int l = threadIdx.x & 63;
  int s = rp[i], epos = rp[i + 1];
  int h = (HEADS == 4) ? (l >> 4) : 0;
  int c0 = 2 * l;

  float ad0, ad1 = 0.f, ad2 = 0.f, ad3 = 0.f;
  if (HEADS == 4){
    float4 adv = *(const float4*)&adb[i * 4];
    ad0 = adv.x; ad1 = adv.y; ad2 = adv.z; ad3 = adv.w;
  } else {
    ad0 = adb[i];
  }

  float den0 = 0.f, den1 = 0.f, den2 = 0.f, den3 = 0.f;
  float acc0 = 0.f, acc1 = 0.f;
  for (int base = s; base < epos; base += 64){
    int j = base + l;
    int myS = 0;
    float w0 = 0.f, w1 = 0.f, w2 = 0.f, w3 = 0.f;
    if (j < epos){
      myS = col[j];
      if (HEADS == 4){
        float4 a4 = *(const float4*)&asb[myS * 4];
        w0 = __expf(lrelu(a4.x + ad0)); den0 += w0;
        w1 = __expf(lrelu(a4.y + ad1)); den1 += w1;
        w2 = __expf(lrelu(a4.z + ad2)); den2 += w2;
        w3 = __expf(lrelu(a4.w + ad3)); den3 += w3;
      } else {
        w0 = __expf(lrelu(asb[myS] + ad0)); den0 += w0;
      }
    }
    sbuf[wid][l] = myS;
    if (HEADS == 4)
      *(float4*)&wbuf[wid][l * 4] = make_float4(w0, w1, w2, w3);
    else
      wbuf[wid][l] = w0;
    __builtin_amdgcn_wave_barrier();
    int cnt = epos - base; if (cnt > 64) cnt = 64;
#pragma unroll 8
    for (int t = 0; t < cnt; ++t){
      int sj = sbuf[wid][t];
      float w = (HEADS == 4) ? wbuf[wid][t * 4 + h] : wbuf[wid][t];
      f16x2 f = *(const f16x2*)&feat[(long long)sj * FDIM + c0];
      acc0 = fmaf(w, (float)f[0], acc0);
      acc1 = fmaf(w, (float)f[1], acc1);
    }
    __builtin_amdgcn_wave_barrier();
  }
  den0 = wsum64(den0);
  if (HEADS == 4){ den1 = wsum64(den1); den2 = wsum64(den2); den3 = wsum64(den3); }
  float dh = (HEADS == 1) ? den0
           : (h < 2 ? (h == 0 ? den0 : den1) : (h == 2 ? den2 : den3));

  float inv = 1.f / (dh + 1e-16f);
  float r0 = fmaf(acc0, inv, bias[c0]);
  float r1 = fmaf(acc1, inv, bias[c0 + 1]);
  float2 rs = *(const float2*)&resid[(long long)i * FDIM + c0];
  float2 o;
  if (MODE == 0){
    float mean = wsum64(r0 + r1) * (1.f / 128.f);
    float dd0 = r0 - mean, dd1 = r1 - mean;
    float var = wsum64(dd0 * dd0 + dd1 * dd1) * (1.f / 128.f);
    float rstd = rsqrtf(var + 1e-5f);
    float p = prw[0];
    float y0 = dd0 * rstd * gamma[c0]     + beta[c0];
    float y1 = dd1 * rstd * gamma[c0 + 1] + beta[c0 + 1];
    y0 = (y0 >= 0.f) ? y0 : p * y0;
    y1 = (y1 >= 0.f) ? y1 : p * y1;
    o.x = y0 + rs.x; o.y = y1 + rs.y;
  } else {
    o.x = r0 + rs.x; o.y = r1 + rs.y;
  }
  *(float2*)&out[(long long)i * FDIM + c0] = o;
}

// ---------------- launch ----------------
static inline int cdiv(int a, int b){ return (a + b - 1) / b; }

extern "C" void kernel_launch(void* const* d_in, const int* in_sizes, int n_in,
                              void* d_out, int out_size, void* d_ws, size_t ws_size,
                              hipStream_t stream){
  const float* x     = (const float*)d_in[0];
  const int*   eidx  = (const int*)d_in[1];
  const float* W0    = (const float*)d_in[2];
  const float* asr0  = (const float*)d_in[3];
  const float* adt0  = (const float*)d_in[4];
  const float* b0    = (const float*)d_in[5];
  const float* g0    = (const float*)d_in[6];
  const float* be0   = (const float*)d_in[7];
  const float* p0    = (const float*)d_in[8];
  const float* W1    = (const float*)d_in[9];
  const float* asr1  = (const float*)d_in[10];
  const float* adt1  = (const float*)d_in[11];
  const float* b1    = (const float*)d_in[12];
  const float* g1    = (const float*)d_in[13];
  const float* be1   = (const float*)d_in[14];
  const float* p1    = (const float*)d_in[15];
  const float* W2    = (const float*)d_in[16];
  const float* asr2  = (const float*)d_in[17];
  const float* adt2  = (const float*)d_in[18];
  const float* b2    = (const float*)d_in[19];

  const int N = in_sizes[0] / FDIM;     // 100000
  const int E = in_sizes[1] / 2;        // 1600000
  const int TOT = E + N;
  const int NB = (N + 127) >> 7;        // buckets of 128 nodes (<=1024)

  char* p = (char*)d_ws;
  auto alloc = [&](size_t bytes) -> void* {
    void* r = (void*)p;
    p += (bytes + 255) & ~(size_t)255;
    return r;
  };
  int*    deg  = (int*)   alloc((size_t)N * 4);
  int*    rp   = (int*)   alloc((size_t)(N + 1) * 4);
  int*    csum = (int*)   alloc(128 * 4);
  int*    bcnt = (int*)   alloc(1024 * 4);
  int*    boff = (int*)   alloc(1025 * 4);
  int*    bcur = (int*)   alloc(1024 * 4);
  int2*   ebuf = (int2*)  alloc((size_t)E * 8);
  int*    col  = (int*)   alloc((size_t)TOT * 4);
  half_t* feat = (half_t*)alloc((size_t)N * FDIM * 2);
  float*  asb  = (float*) alloc((size_t)N * 4 * 4);
  float*  adb  = (float*) alloc((size_t)N * 4 * 4);
  float*  hA   = (float*) alloc((size_t)N * FDIM * 4);
  float*  hB   = (float*) alloc((size_t)N * FDIM * 4);
  (void)ws_size; (void)n_in; (void)out_size;

  const int nch = cdiv(N, 1024);
  const int SBLK = 256;                 // blocks for bucket passes
  const int chunk = cdiv(E, SBLK);

  // ---- CSR build (dst-sorted, shared by all 3 layers) ----
  k_bzero<<<cdiv(NB, 256), 256, 0, stream>>>(bcnt, NB);
  k_bp1<<<SBLK, 256, 0, stream>>>(eidx + E, bcnt, E, chunk);
  k_bscan<<<1, 256, 0, stream>>>(bcnt, boff, bcur, NB, E);
  k_bp2<<<SBLK, 256, 0, stream>>>(eidx, eidx + E, bcur, ebuf, E, chunk);
  k_bdeg<<<NB, 256, 0, stream>>>(ebuf, boff, deg, N);
  k_scan1<<<nch, 256, 0, stream>>>(deg, rp, csum, N);
  k_scan2<<<1, 128, 0, stream>>>(csum, nch);
  k_scan3<<<cdiv(N + 1, 256), 256, 0, stream>>>(rp, csum, N, TOT);
  k_bfill<<<NB, 256, 0, stream>>>(ebuf, boff, rp, col, N);

  const int gB = cdiv(N, 128);  // mfma gemm blocks
  const int nB = cdiv(N, 4);    // node-wave blocks (4 waves/block)

  // ---- block 0 ----
  gemm_mfma<4><<<gB, 256, 0, stream>>>(x, W0, asr0, adt0, feat, asb, adb, N);
  k_agg<4, 0><<<nB, 256, 0, stream>>>(feat, asb, adb, rp, col, b0, g0, be0, p0, x, hA, N);
  // ---- block 1 ----
  gemm_mfma<4><<<gB, 256, 0, stream>>>(hA, W1, asr1, adt1, feat, asb, adb, N);
  k_agg<4, 0><<<nB, 256, 0, stream>>>(feat, asb, adb, rp, col, b1, g1, be1, p1, hA, hB, N);
  // ---- block 2 ----
  gemm_mfma<1><<<gB, 256, 0, stream>>>(hB, W2, asr2, adt2, feat, asb, adb, N);
  k_agg<1, 1><<<nB, 256, 0, stream>>>(feat, asb, adb, rp, col, b2, nullptr, nullptr,
                                      nullptr, hB, (float*)d_out, N);
}